// Round 11
// baseline (290.004 us; speedup 1.0000x reference)
//
#include <hip/hip_runtime.h>
#include <hip/hip_bf16.h>
#include <math.h>

#define TOKS 4096

typedef __attribute__((ext_vector_type(4))) float    f32x4;
typedef __attribute__((ext_vector_type(8))) short    short8;
typedef __attribute__((ext_vector_type(4))) unsigned short ushort4v;
typedef unsigned short ushort;

__device__ __forceinline__ ushort f2b(float f) {   // f32 -> bf16 bits, RNE
    unsigned int b = __float_as_uint(f);
    b += 0x7fff + ((b >> 16) & 1);
    return (ushort)(b >> 16);
}

// ---------------------------------------------------------------------------
// Kernel 0: pack routing weights: Wb[96][1024] bf16 = [dw(84 rows) ; gate_w^T]
// ---------------------------------------------------------------------------
__global__ __launch_bounds__(256) void wb_kernel(
    const float* __restrict__ dw,      // [84][1024]
    const float* __restrict__ gate_w,  // [1024][12]
    ushort* __restrict__ Wb)           // [96][1024] bf16
{
    const int i = blockIdx.x * 256 + threadIdx.x;   // 48 blocks: 96*1024/8
    const int row = i >> 7, k0 = (i & 127) * 8;
    short8 o;
    if (row < 84) {
        float4 a0 = *(const float4*)&dw[(size_t)row*1024 + k0];
        float4 a1 = *(const float4*)&dw[(size_t)row*1024 + k0 + 4];
        o[0]=(short)f2b(a0.x); o[1]=(short)f2b(a0.y); o[2]=(short)f2b(a0.z); o[3]=(short)f2b(a0.w);
        o[4]=(short)f2b(a1.x); o[5]=(short)f2b(a1.y); o[6]=(short)f2b(a1.z); o[7]=(short)f2b(a1.w);
    } else {
        const int t = row - 84;
        #pragma unroll
        for (int j = 0; j < 8; ++j) o[j] = (short)f2b(gate_w[(size_t)(k0+j)*12 + t]);
    }
    *(short8*)&Wb[(size_t)row*1024 + k0] = o;
}

// ---------------------------------------------------------------------------
// Kernel 1: fused routing: logits = x @ Wb^T via MFMA (1 wave / 16 tokens),
// then in-block sigmoid/leaf-prob/gate-softmax postprocess -> coeffb bf16.
// ---------------------------------------------------------------------------
__global__ __launch_bounds__(64) void route2_kernel(
    const float* __restrict__ x,        // [4096][1024]
    const ushort* __restrict__ Wb,      // [96][1024] bf16
    const float* __restrict__ db,       // [84]
    const float* __restrict__ ntl,      // [84]
    const float* __restrict__ gate_b,   // [12]
    ushort* __restrict__ coeffb)        // [4096][96] bf16
{
    const int tok0 = blockIdx.x * 16;
    const int lane = threadIdx.x;
    const int lq = lane & 15, lg = lane >> 4;
    __shared__ float lgt[16][97];       // logits [token][96], pad 97

    f32x4 acc[6];
    #pragma unroll
    for (int n = 0; n < 6; ++n) acc[n] = (f32x4){0.f,0.f,0.f,0.f};

    for (int k0 = 0; k0 < 1024; k0 += 32) {
        float4 a0 = *(const float4*)&x[(size_t)(tok0 + lq)*1024 + k0 + lg*8];
        float4 a1 = *(const float4*)&x[(size_t)(tok0 + lq)*1024 + k0 + lg*8 + 4];
        short8 af;
        af[0]=(short)f2b(a0.x); af[1]=(short)f2b(a0.y); af[2]=(short)f2b(a0.z); af[3]=(short)f2b(a0.w);
        af[4]=(short)f2b(a1.x); af[5]=(short)f2b(a1.y); af[6]=(short)f2b(a1.z); af[7]=(short)f2b(a1.w);
        #pragma unroll
        for (int n = 0; n < 6; ++n) {
            short8 bf_ = *(const short8*)&Wb[(size_t)(n*16 + lq)*1024 + k0 + lg*8];
            acc[n] = __builtin_amdgcn_mfma_f32_16x16x32_bf16(af, bf_, acc[n], 0, 0, 0);
        }
    }

    // C frag -> LDS: token = lg*4+r, col = n*16+lq
    #pragma unroll
    for (int n = 0; n < 6; ++n)
        #pragma unroll
        for (int r = 0; r < 4; ++r)
            lgt[lg*4 + r][n*16 + lq] = acc[n][r];
    __builtin_amdgcn_wave_barrier();

    // postprocess: 64 threads x 3 (tok,tree) jobs
    const int tok = lane >> 2;
    #pragma unroll
    for (int tj = 0; tj < 3; ++tj) {
        const int t = (lane & 3)*3 + tj;
        float dec[7];
        #pragma unroll
        for (int n = 0; n < 7; ++n) {
            float tempv = log1pf(expf(ntl[t*7+n] + 0.5413f));
            float v = (lgt[tok][t*7+n] + db[t*7+n]) / tempv;
            dec[n] = 1.f / (1.f + expf(-v));
        }
        float g[12], gmax = -3e38f;
        #pragma unroll
        for (int tt = 0; tt < 12; ++tt) {
            g[tt] = lgt[tok][84+tt] + gate_b[tt];
            gmax = fmaxf(gmax, g[tt]);
        }
        float gsum = 0.f;
        #pragma unroll
        for (int tt = 0; tt < 12; ++tt) gsum += expf(g[tt]-gmax);
        const float wgt = expf(g[t]-gmax) / gsum;
        short8 co;
        #pragma unroll
        for (int l = 0; l < 8; ++l) {
            float p = wgt; int node = 0;
            #pragma unroll
            for (int dpt = 0; dpt < 3; ++dpt) {
                int bit = (l >> (2-dpt)) & 1;
                float r = dec[node];
                p *= bit ? (1.f - r) : r;
                node = 2*node + 1 + bit;
            }
            co[l] = (short)f2b(p);
        }
        *(short8*)&coeffb[(size_t)(tok0 + tok)*96 + t*8] = co;
    }
}

// ---------------------------------------------------------------------------
// Kernel 2: leaf [3][96][1024] f32 -> leafT [3][1024][96] bf16
// ---------------------------------------------------------------------------
__global__ __launch_bounds__(256) void lt_kernel(
    const float* __restrict__ leaf, ushort* __restrict__ leafT)
{
    __shared__ float t[96][65];
    const int d0 = blockIdx.x * 64, h = blockIdx.y;
    const int tid = threadIdx.x;
    for (int i = tid; i < 96*16; i += 256) {
        int k = i >> 4, c4 = i & 15;
        *(float4*)&t[k][c4*4] = *(const float4*)&leaf[(size_t)(h*96 + k)*1024 + d0 + c4*4];
    }
    __syncthreads();
    const int d = tid >> 2, kq = (tid & 3) * 24;
    #pragma unroll
    for (int base = 0; base < 24; base += 8) {
        short8 o;
        #pragma unroll
        for (int j = 0; j < 8; ++j) o[j] = (short)f2b(t[kq+base+j][d]);
        *(short8*)&leafT[(size_t)(h*1024 + d0 + d)*96 + kq + base] = o;
    }
}

// ---------------------------------------------------------------------------
// Kernel 3: MFMA mix. C rows = d (leaf dim), cols = token.
// Q,K planes -> qkvb (8B vector stores); V plane -> vT directly.
// ---------------------------------------------------------------------------
__global__ __launch_bounds__(256) void mix_kernel(
    const ushort* __restrict__ coeffb,  // [4096][96] bf16
    const ushort* __restrict__ leafT,   // [3][1024][96] bf16
    ushort* __restrict__ qkvb,          // [2][4096][1024] bf16 (Q,K)
    ushort* __restrict__ vT)            // [64][64][1024] bf16
{
    const int bt = blockIdx.x;          // 64 token tiles of 64
    const int bd = blockIdx.y;          // 24 col tiles of 128 over 3072
    const int tid = threadIdx.x, w = tid >> 6, lane = tid & 63;
    const int lq = lane & 15, lg = lane >> 4;
    const int tok0 = bt*64 + w*16;
    const int c0 = bd*128;
    const int pl = c0 >> 10;            // 0=Q,1=K,2=V
    const int d0 = c0 & 1023;

    f32x4 acc[8];
    #pragma unroll
    for (int n = 0; n < 8; ++n) acc[n] = (f32x4){0.f,0.f,0.f,0.f};

    #pragma unroll
    for (int ks = 0; ks < 3; ++ks) {
        const int k0 = ks*32;
        short8 bfrag = *(const short8*)&coeffb[(tok0 + lq)*96 + k0 + lg*8];
        #pragma unroll
        for (int n = 0; n < 8; ++n) {
            short8 afrag = *(const short8*)&leafT[(size_t)(pl*1024 + d0 + n*16 + lq)*96 + k0 + lg*8];
            acc[n] = __builtin_amdgcn_mfma_f32_16x16x32_bf16(afrag, bfrag, acc[n], 0, 0, 0);
        }
    }

    const int tok = tok0 + lq;
    if (pl < 2) {
        #pragma unroll
        for (int n = 0; n < 8; ++n) {
            const int d = d0 + n*16 + lg*4;
            ushort4v u;
            u[0]=f2b(acc[n][0]); u[1]=f2b(acc[n][1]);
            u[2]=f2b(acc[n][2]); u[3]=f2b(acc[n][3]);
            *(ushort4v*)&qkvb[(size_t)pl*TOKS*1024 + (size_t)tok*1024 + d] = u;
        }
    } else {
        const int b = tok >> 10, seq = tok & 1023;
        #pragma unroll
        for (int n = 0; n < 8; ++n) {
            #pragma unroll
            for (int r = 0; r < 4; ++r) {
                const int d = d0 + n*16 + lg*4 + r;
                const int head = d >> 6, dh = d & 63;
                vT[((size_t)((b*16+head)*64 + dh))*1024 + seq] = f2b(acc[n][r]);
            }
        }
    }
}

// ---------------------------------------------------------------------------
// Kernel 4: out_w [1024][1024] f32 -> wT [n][k] bf16 (transpose + convert)
// ---------------------------------------------------------------------------
__global__ __launch_bounds__(256) void wtrans_kernel(
    const float* __restrict__ w, ushort* __restrict__ wT)
{
    __shared__ float t[64][65];
    const int n0 = blockIdx.x * 64, k0 = blockIdx.y * 64;
    const int tid = threadIdx.x;
    const int r = tid >> 2, c16 = (tid & 3) * 16;
    #pragma unroll
    for (int j = 0; j < 16; j += 4)
        *(float4*)&t[r][c16+j] = *(const float4*)&w[(size_t)(k0+r)*1024 + n0 + c16 + j];
    __syncthreads();
    short8 o0, o1;
    #pragma unroll
    for (int j = 0; j < 8; ++j) o0[j] = (short)f2b(t[c16+j][r]);
    #pragma unroll
    for (int j = 0; j < 8; ++j) o1[j] = (short)f2b(t[c16+8+j][r]);
    *(short8*)&wT[(size_t)(n0+r)*1024 + k0 + c16]     = o0;
    *(short8*)&wT[(size_t)(n0+r)*1024 + k0 + c16 + 8] = o1;
}

// ---------------------------------------------------------------------------
// Kernel 5: MFMA flash attention, single-wave blocks (64 thr, 16 q-rows),
// KVBLK=128: one softmax reduce/rescale pass per 128 keys, 32 loads in
// flight per tile. uint-typed pTu staging (TBAA-safe), wave_barrier ordering,
// LPT descending-qt dispatch + bh%8 XCD affinity.
// ---------------------------------------------------------------------------
__global__ __launch_bounds__(64) void attn_kernel(
    const ushort* __restrict__ qk,    // [2][4096][1024] bf16 (Q,K planes)
    const ushort* __restrict__ vT,    // [64][64][1024] bf16
    ushort* __restrict__ ctxb)        // [4096][1024] bf16
{
    const int id = blockIdx.x;
    const int bh = id & 63;
    const int qt = 63 - (id >> 6);    // q-tile (16 rows), descending work
    const int b = bh >> 4, h = bh & 15;
    const int lane = threadIdx.x;
    const int lq = lane & 15, lg = lane >> 4;
    __shared__ unsigned int pTu[128][13];  // P^T staging: [k][q-pair], uint-only

    const size_t plane = (size_t)TOKS*1024;
    const int tokq = b*1024 + qt*16 + lq;
    short8 aq[2];
    aq[0] = *(const short8*)&qk[(size_t)tokq*1024 + h*64 + lg*8];
    aq[1] = *(const short8*)&qk[(size_t)tokq*1024 + h*64 + 32 + lg*8];

    f32x4 o[4];
    #pragma unroll
    for (int n = 0; n < 4; ++n) o[n] = (f32x4){0.f,0.f,0.f,0.f};
    float m[4] = {-3e38f,-3e38f,-3e38f,-3e38f};
    float l[4] = {0.f,0.f,0.f,0.f};

    const ushort* Kp  = qk + plane;
    const ushort* vTp = vT + (size_t)bh*64*1024;
    const int nt = (qt >> 3) + 1;     // 128-wide KV tiles

    for (int t = 0; t < nt; ++t) {
        const int tk0 = b*1024 + t*128;
        f32x4 s[8];
        #pragma unroll
        for (int n = 0; n < 8; ++n) s[n] = (f32x4){0.f,0.f,0.f,0.f};
        #pragma unroll
        for (int kk = 0; kk < 2; ++kk)
            #pragma unroll
            for (int n = 0; n < 8; ++n) {
                short8 bk = *(const short8*)&Kp[(size_t)(tk0 + n*16 + lq)*1024 + h*64 + kk*32 + lg*8];
                s[n] = __builtin_amdgcn_mfma_f32_16x16x32_bf16(aq[kk], bk, s[n], 0, 0, 0);
            }

        // scale + causal mask: q = qt*16 + lg*4 + r, k = t*128 + n*16 + lq
        const bool diag = (t == nt-1);
        if (diag) {
            #pragma unroll
            for (int n = 0; n < 8; ++n)
                #pragma unroll
                for (int r = 0; r < 4; ++r) {
                    float v = s[n][r] * 0.125f;
                    if (t*128 + n*16 + lq > qt*16 + lg*4 + r) v = -1e9f;
                    s[n][r] = v;
                }
        } else {
            #pragma unroll
            for (int n = 0; n < 8; ++n)
                #pragma unroll
                for (int r = 0; r < 4; ++r) s[n][r] *= 0.125f;
        }

        #pragma unroll
        for (int r = 0; r < 4; ++r) {
            float rm = fmaxf(fmaxf(fmaxf(s[0][r], s[1][r]), fmaxf(s[2][r], s[3][r])),
                             fmaxf(fmaxf(s[4][r], s[5][r]), fmaxf(s[6][r], s[7][r])));
            rm = fmaxf(rm, __shfl_xor(rm, 1));
            rm = fmaxf(rm, __shfl_xor(rm, 2));
            rm = fmaxf(rm, __shfl_xor(rm, 4));
            rm = fmaxf(rm, __shfl_xor(rm, 8));
            float mnew = fmaxf(m[r], rm);
            float corr = __expf(m[r] - mnew);
            float ps = 0.f;
            #pragma unroll
            for (int n = 0; n < 8; ++n) {
                float p = __expf(s[n][r] - mnew);
                s[n][r] = p; ps += p;
            }
            ps += __shfl_xor(ps, 1);
            ps += __shfl_xor(ps, 2);
            ps += __shfl_xor(ps, 4);
            ps += __shfl_xor(ps, 8);
            l[r] = l[r]*corr + ps;
            m[r] = mnew;
            o[0][r] *= corr; o[1][r] *= corr; o[2][r] *= corr; o[3][r] *= corr;
        }

        // P (bf16-packed) -> pTu[k][q/2] (uint writes, same-wave FIFO)
        #pragma unroll
        for (int n = 0; n < 8; ++n) {
            unsigned int lo = (unsigned int)f2b(s[n][0]) | ((unsigned int)f2b(s[n][1]) << 16);
            unsigned int hi = (unsigned int)f2b(s[n][2]) | ((unsigned int)f2b(s[n][3]) << 16);
            pTu[n*16 + lq][lg*2]     = lo;
            pTu[n*16 + lq][lg*2 + 1] = hi;
        }
        __builtin_amdgcn_wave_barrier();

        short8 pa[4];
        #pragma unroll
        for (int kk = 0; kk < 4; ++kk)
            #pragma unroll
            for (int j = 0; j < 8; ++j) {
                unsigned int u = pTu[kk*32 + lg*8 + j][lq >> 1];
                pa[kk][j] = (short)(ushort)(u >> ((lq & 1) * 16));
            }
        __builtin_amdgcn_wave_barrier();

        #pragma unroll
        for (int kk = 0; kk < 4; ++kk)
            #pragma unroll
            for (int n = 0; n < 4; ++n) {
                short8 bv = *(const short8*)&vTp[(size_t)(n*16 + lq)*1024 + t*128 + kk*32 + lg*8];
                o[n] = __builtin_amdgcn_mfma_f32_16x16x32_bf16(pa[kk], bv, o[n], 0, 0, 0);
            }
    }

    #pragma unroll
    for (int r = 0; r < 4; ++r) {
        float inv = 1.f / l[r];
        int row = b*1024 + qt*16 + lg*4 + r;
        #pragma unroll
        for (int n = 0; n < 4; ++n)
            ctxb[(size_t)row*1024 + h*64 + n*16 + lq] = f2b(o[n][r] * inv);
    }
}

// ---------------------------------------------------------------------------
// Kernel 6: out = ctx(bf16) @ wT(bf16)^T + bias, MFMA. 128x64 block tile,
// grid (16,32)=512 blocks (2/CU -> 2 waves/SIMD TLP). Wave = 64x32 output.
// ---------------------------------------------------------------------------
__global__ __launch_bounds__(256) void proj_kernel(
    const ushort* __restrict__ A,     // ctx bf16 [4096][1024]
    const ushort* __restrict__ Bt,    // wT bf16 [1024(n)][1024(k)]
    const float* __restrict__ bias,   // [1024]
    float* __restrict__ out)          // [4096][1024]
{
    const int bn = blockIdx.x, bm = blockIdx.y;
    const int tid = threadIdx.x, w = tid >> 6, lane = tid & 63;
    const int wm = w >> 1, wn = w & 1;
    const int lq = lane & 15, lg = lane >> 4;
    const int row0 = bm*128 + wm*64;
    const int col0 = bn*64 + wn*32;

    f32x4 acc[4][2];
    #pragma unroll
    for (int i = 0; i < 4; ++i)
        #pragma unroll
        for (int j = 0; j < 2; ++j) acc[i][j] = (f32x4){0.f,0.f,0.f,0.f};

    for (int k0 = 0; k0 < 1024; k0 += 32) {
        short8 a[4], bfr[2];
        #pragma unroll
        for (int i = 0; i < 4; ++i)
            a[i] = *(const short8*)&A[(size_t)(row0 + i*16 + lq)*1024 + k0 + lg*8];
        #pragma unroll
        for (int j = 0; j < 2; ++j)
            bfr[j] = *(const short8*)&Bt[(size_t)(col0 + j*16 + lq)*1024 + k0 + lg*8];
        #pragma unroll
        for (int i = 0; i < 4; ++i)
            #pragma unroll
            for (int j = 0; j < 2; ++j)
                acc[i][j] = __builtin_amdgcn_mfma_f32_16x16x32_bf16(a[i], bfr[j], acc[i][j], 0, 0, 0);
    }

    #pragma unroll
    for (int i = 0; i < 4; ++i)
        #pragma unroll
        for (int j = 0; j < 2; ++j) {
            int col = col0 + j*16 + lq;
            float bb = bias[col];
            #pragma unroll
            for (int r = 0; r < 4; ++r)
                out[(size_t)(row0 + i*16 + lg*4 + r)*1024 + col] = acc[i][j][r] + bb;
        }
}

// ---------------------------------------------------------------------------
extern "C" void kernel_launch(void* const* d_in, const int* in_sizes, int n_in,
                              void* d_out, int out_size, void* d_ws, size_t ws_size,
                              hipStream_t stream) {
    (void)in_sizes; (void)n_in; (void)out_size; (void)ws_size;
    const float* x      = (const float*)d_in[0];
    const float* dw     = (const float*)d_in[1];
    const float* db     = (const float*)d_in[2];
    const float* ntl    = (const float*)d_in[3];
    const float* gate_w = (const float*)d_in[4];
    const float* gate_b = (const float*)d_in[5];
    const float* leaf   = (const float*)d_in[6];
    const float* out_w  = (const float*)d_in[7];
    const float* out_b  = (const float*)d_in[8];
    float* out = (float*)d_out;

    // ws layout (bytes): coeffb@0 (0.75MB) | Wb@1MB (0.2MB) | qkvb@2MB (16MB)
    //                    vT@20MB (8MB) | ctxb@30MB (8MB) | wT@40MB (2MB) | leafT@44MB (0.6MB)
    ushort* coeffb = (ushort*)d_ws;
    ushort* Wb     = (ushort*)((char*)d_ws + ((size_t)1u  << 20));
    ushort* qkvb   = (ushort*)((char*)d_ws + ((size_t)2u  << 20));
    ushort* vT     = (ushort*)((char*)d_ws + ((size_t)20u << 20));
    ushort* ctxb   = (ushort*)((char*)d_ws + ((size_t)30u << 20));
    ushort* wT     = (ushort*)((char*)d_ws + ((size_t)40u << 20));
    ushort* leafT  = (ushort*)((char*)d_ws + ((size_t)44u << 20));

    hipLaunchKernelGGL(wb_kernel,      dim3(48),      dim3(256), 0, stream,
                       dw, gate_w, Wb);
    hipLaunchKernelGGL(lt_kernel,      dim3(16, 3),   dim3(256), 0, stream,
                       leaf, leafT);
    hipLaunchKernelGGL(wtrans_kernel,  dim3(16, 16),  dim3(256), 0, stream,
                       out_w, wT);
    hipLaunchKernelGGL(route2_kernel,  dim3(256),     dim3(64),  0, stream,
                       x, Wb, db, ntl, gate_b, coeffb);
    hipLaunchKernelGGL(mix_kernel,     dim3(64, 24),  dim3(256), 0, stream,
                       coeffb, leafT, qkvb, vT);
    hipLaunchKernelGGL(attn_kernel,    dim3(4096),    dim3(64),  0, stream,
                       qkvb, vT, ctxb);
    hipLaunchKernelGGL(proj_kernel,    dim3(16, 32),  dim3(256), 0, stream,
                       ctxb, wT, out_b, out);
}

// Round 13
// 244.635 us; speedup vs baseline: 1.1855x; 1.1855x over previous
//
#include <hip/hip_runtime.h>
#include <hip/hip_bf16.h>
#include <math.h>

#define TOKS 4096

typedef __attribute__((ext_vector_type(4))) float    f32x4;
typedef __attribute__((ext_vector_type(8))) short    short8;
typedef __attribute__((ext_vector_type(4))) unsigned short ushort4v;
typedef unsigned short ushort;

__device__ __forceinline__ ushort f2b(float f) {   // f32 -> bf16 bits, RNE
    unsigned int b = __float_as_uint(f);
    b += 0x7fff + ((b >> 16) & 1);
    return (ushort)(b >> 16);
}

// ---------------------------------------------------------------------------
// Kernel 0: pack routing weights: Wb[96][1024] bf16 = [dw(84 rows) ; gate_w^T]
// ---------------------------------------------------------------------------
__global__ __launch_bounds__(256) void wb_kernel(
    const float* __restrict__ dw,      // [84][1024]
    const float* __restrict__ gate_w,  // [1024][12]
    ushort* __restrict__ Wb)           // [96][1024] bf16
{
    const int i = blockIdx.x * 256 + threadIdx.x;   // 48 blocks: 96*1024/8
    const int row = i >> 7, k0 = (i & 127) * 8;
    short8 o;
    if (row < 84) {
        float4 a0 = *(const float4*)&dw[(size_t)row*1024 + k0];
        float4 a1 = *(const float4*)&dw[(size_t)row*1024 + k0 + 4];
        o[0]=(short)f2b(a0.x); o[1]=(short)f2b(a0.y); o[2]=(short)f2b(a0.z); o[3]=(short)f2b(a0.w);
        o[4]=(short)f2b(a1.x); o[5]=(short)f2b(a1.y); o[6]=(short)f2b(a1.z); o[7]=(short)f2b(a1.w);
    } else {
        const int t = row - 84;
        #pragma unroll
        for (int j = 0; j < 8; ++j) o[j] = (short)f2b(gate_w[(size_t)(k0+j)*12 + t]);
    }
    *(short8*)&Wb[(size_t)row*1024 + k0] = o;
}

// ---------------------------------------------------------------------------
// Kernel 1: fused routing, K-split across 8 waves (512 thr, 16 tokens/block).
// Each wave: K-slice of 128 (4 k-steps) -> partial C in LDS -> cross-wave
// reduce -> sigmoid/leaf-prob/gate-softmax postprocess -> coeffb bf16.
// Fixes round-11's 105us: 1 wave/CU zero-TLP + 32-step dependent chain.
// ---------------------------------------------------------------------------
__global__ __launch_bounds__(512) void route3_kernel(
    const float* __restrict__ x,        // [4096][1024]
    const ushort* __restrict__ Wb,      // [96][1024] bf16
    const float* __restrict__ db,       // [84]
    const float* __restrict__ ntl,      // [84]
    const float* __restrict__ gate_b,   // [12]
    ushort* __restrict__ coeffb)        // [4096][96] bf16
{
    const int tok0 = blockIdx.x * 16;
    const int tid  = threadIdx.x;
    const int wv   = tid >> 6;          // 0..7 = K-slice
    const int lane = tid & 63;
    const int lq = lane & 15, lg = lane >> 4;
    __shared__ float part[8][16][100];  // 51.2 KB; write 2-way conflict (free)

    f32x4 acc[6];
    #pragma unroll
    for (int n = 0; n < 6; ++n) acc[n] = (f32x4){0.f,0.f,0.f,0.f};

    const int kbase = wv * 128;
    #pragma unroll
    for (int ks = 0; ks < 4; ++ks) {
        const int k0 = kbase + ks*32;
        float4 a0 = *(const float4*)&x[(size_t)(tok0 + lq)*1024 + k0 + lg*8];
        float4 a1 = *(const float4*)&x[(size_t)(tok0 + lq)*1024 + k0 + lg*8 + 4];
        short8 af;
        af[0]=(short)f2b(a0.x); af[1]=(short)f2b(a0.y); af[2]=(short)f2b(a0.z); af[3]=(short)f2b(a0.w);
        af[4]=(short)f2b(a1.x); af[5]=(short)f2b(a1.y); af[6]=(short)f2b(a1.z); af[7]=(short)f2b(a1.w);
        #pragma unroll
        for (int n = 0; n < 6; ++n) {
            short8 bf_ = *(const short8*)&Wb[(size_t)(n*16 + lq)*1024 + k0 + lg*8];
            acc[n] = __builtin_amdgcn_mfma_f32_16x16x32_bf16(af, bf_, acc[n], 0, 0, 0);
        }
    }

    // partial C -> LDS: token = lg*4+r, outcol = n*16+lq
    #pragma unroll
    for (int n = 0; n < 6; ++n)
        #pragma unroll
        for (int r = 0; r < 4; ++r)
            part[wv][lg*4 + r][n*16 + lq] = acc[n][r];
    __syncthreads();

    // reduce 8 K-slices: 16*96 = 1536 sums over 512 threads (3 each)
    for (int i = tid; i < 1536; i += 512) {
        const int tk = i / 96, c = i - tk*96;
        float s = part[0][tk][c];
        #pragma unroll
        for (int w = 1; w < 8; ++w) s += part[w][tk][c];
        part[0][tk][c] = s;
    }
    __syncthreads();

    // postprocess: 192 threads = 16 tokens x 12 trees
    if (tid < 192) {
        const int lt = tid / 12, t = tid - lt*12;
        float dec[7];
        #pragma unroll
        for (int n = 0; n < 7; ++n) {
            float tempv = log1pf(expf(ntl[t*7+n] + 0.5413f));
            float v = (part[0][lt][t*7+n] + db[t*7+n]) / tempv;
            dec[n] = 1.f / (1.f + expf(-v));
        }
        float g[12], gmax = -3e38f;
        #pragma unroll
        for (int tt = 0; tt < 12; ++tt) {
            g[tt] = part[0][lt][84+tt] + gate_b[tt];
            gmax = fmaxf(gmax, g[tt]);
        }
        float gsum = 0.f;
        #pragma unroll
        for (int tt = 0; tt < 12; ++tt) gsum += expf(g[tt]-gmax);
        const float wgt = expf(g[t]-gmax) / gsum;
        short8 co;
        #pragma unroll
        for (int l = 0; l < 8; ++l) {
            float p = wgt; int node = 0;
            #pragma unroll
            for (int dpt = 0; dpt < 3; ++dpt) {
                int bit = (l >> (2-dpt)) & 1;
                float r = dec[node];
                p *= bit ? (1.f - r) : r;
                node = 2*node + 1 + bit;
            }
            co[l] = (short)f2b(p);
        }
        *(short8*)&coeffb[(size_t)(tok0 + lt)*96 + t*8] = co;
    }
}

// ---------------------------------------------------------------------------
// Kernel 2: leaf [3][96][1024] f32 -> leafT [3][1024][96] bf16
// ---------------------------------------------------------------------------
__global__ __launch_bounds__(256) void lt_kernel(
    const float* __restrict__ leaf, ushort* __restrict__ leafT)
{
    __shared__ float t[96][65];
    const int d0 = blockIdx.x * 64, h = blockIdx.y;
    const int tid = threadIdx.x;
    for (int i = tid; i < 96*16; i += 256) {
        int k = i >> 4, c4 = i & 15;
        *(float4*)&t[k][c4*4] = *(const float4*)&leaf[(size_t)(h*96 + k)*1024 + d0 + c4*4];
    }
    __syncthreads();
    const int d = tid >> 2, kq = (tid & 3) * 24;
    #pragma unroll
    for (int base = 0; base < 24; base += 8) {
        short8 o;
        #pragma unroll
        for (int j = 0; j < 8; ++j) o[j] = (short)f2b(t[kq+base+j][d]);
        *(short8*)&leafT[(size_t)(h*1024 + d0 + d)*96 + kq + base] = o;
    }
}

// ---------------------------------------------------------------------------
// Kernel 3: MFMA mix. C rows = d (leaf dim), cols = token.
// Q,K planes -> qkvb (8B vector stores); V plane -> vT directly.
// ---------------------------------------------------------------------------
__global__ __launch_bounds__(256) void mix_kernel(
    const ushort* __restrict__ coeffb,  // [4096][96] bf16
    const ushort* __restrict__ leafT,   // [3][1024][96] bf16
    ushort* __restrict__ qkvb,          // [2][4096][1024] bf16 (Q,K)
    ushort* __restrict__ vT)            // [64][64][1024] bf16
{
    const int bt = blockIdx.x;          // 64 token tiles of 64
    const int bd = blockIdx.y;          // 24 col tiles of 128 over 3072
    const int tid = threadIdx.x, w = tid >> 6, lane = tid & 63;
    const int lq = lane & 15, lg = lane >> 4;
    const int tok0 = bt*64 + w*16;
    const int c0 = bd*128;
    const int pl = c0 >> 10;            // 0=Q,1=K,2=V
    const int d0 = c0 & 1023;

    f32x4 acc[8];
    #pragma unroll
    for (int n = 0; n < 8; ++n) acc[n] = (f32x4){0.f,0.f,0.f,0.f};

    #pragma unroll
    for (int ks = 0; ks < 3; ++ks) {
        const int k0 = ks*32;
        short8 bfrag = *(const short8*)&coeffb[(tok0 + lq)*96 + k0 + lg*8];
        #pragma unroll
        for (int n = 0; n < 8; ++n) {
            short8 afrag = *(const short8*)&leafT[(size_t)(pl*1024 + d0 + n*16 + lq)*96 + k0 + lg*8];
            acc[n] = __builtin_amdgcn_mfma_f32_16x16x32_bf16(afrag, bfrag, acc[n], 0, 0, 0);
        }
    }

    const int tok = tok0 + lq;
    if (pl < 2) {
        #pragma unroll
        for (int n = 0; n < 8; ++n) {
            const int d = d0 + n*16 + lg*4;
            ushort4v u;
            u[0]=f2b(acc[n][0]); u[1]=f2b(acc[n][1]);
            u[2]=f2b(acc[n][2]); u[3]=f2b(acc[n][3]);
            *(ushort4v*)&qkvb[(size_t)pl*TOKS*1024 + (size_t)tok*1024 + d] = u;
        }
    } else {
        const int b = tok >> 10, seq = tok & 1023;
        #pragma unroll
        for (int n = 0; n < 8; ++n) {
            #pragma unroll
            for (int r = 0; r < 4; ++r) {
                const int d = d0 + n*16 + lg*4 + r;
                const int head = d >> 6, dh = d & 63;
                vT[((size_t)((b*16+head)*64 + dh))*1024 + seq] = f2b(acc[n][r]);
            }
        }
    }
}

// ---------------------------------------------------------------------------
// Kernel 4: out_w [1024][1024] f32 -> wT [n][k] bf16 (transpose + convert)
// ---------------------------------------------------------------------------
__global__ __launch_bounds__(256) void wtrans_kernel(
    const float* __restrict__ w, ushort* __restrict__ wT)
{
    __shared__ float t[64][65];
    const int n0 = blockIdx.x * 64, k0 = blockIdx.y * 64;
    const int tid = threadIdx.x;
    const int r = tid >> 2, c16 = (tid & 3) * 16;
    #pragma unroll
    for (int j = 0; j < 16; j += 4)
        *(float4*)&t[r][c16+j] = *(const float4*)&w[(size_t)(k0+r)*1024 + n0 + c16 + j];
    __syncthreads();
    short8 o0, o1;
    #pragma unroll
    for (int j = 0; j < 8; ++j) o0[j] = (short)f2b(t[c16+j][r]);
    #pragma unroll
    for (int j = 0; j < 8; ++j) o1[j] = (short)f2b(t[c16+8+j][r]);
    *(short8*)&wT[(size_t)(n0+r)*1024 + k0 + c16]     = o0;
    *(short8*)&wT[(size_t)(n0+r)*1024 + k0 + c16 + 8] = o1;
}

// ---------------------------------------------------------------------------
// Kernel 5: MFMA flash attention, single-wave blocks (64 thr, 16 q-rows),
// KVBLK=128. uint-typed pTu staging (TBAA-safe), wave_barrier ordering,
// LPT descending-qt dispatch + bh%8 XCD affinity.
// ---------------------------------------------------------------------------
__global__ __launch_bounds__(64) void attn_kernel(
    const ushort* __restrict__ qk,    // [2][4096][1024] bf16 (Q,K planes)
    const ushort* __restrict__ vT,    // [64][64][1024] bf16
    ushort* __restrict__ ctxb)        // [4096][1024] bf16
{
    const int id = blockIdx.x;
    const int bh = id & 63;
    const int qt = 63 - (id >> 6);    // q-tile (16 rows), descending work
    const int b = bh >> 4, h = bh & 15;
    const int lane = threadIdx.x;
    const int lq = lane & 15, lg = lane >> 4;
    __shared__ unsigned int pTu[128][13];  // P^T staging: [k][q-pair], uint-only

    const size_t plane = (size_t)TOKS*1024;
    const int tokq = b*1024 + qt*16 + lq;
    short8 aq[2];
    aq[0] = *(const short8*)&qk[(size_t)tokq*1024 + h*64 + lg*8];
    aq[1] = *(const short8*)&qk[(size_t)tokq*1024 + h*64 + 32 + lg*8];

    f32x4 o[4];
    #pragma unroll
    for (int n = 0; n < 4; ++n) o[n] = (f32x4){0.f,0.f,0.f,0.f};
    float m[4] = {-3e38f,-3e38f,-3e38f,-3e38f};
    float l[4] = {0.f,0.f,0.f,0.f};

    const ushort* Kp  = qk + plane;
    const ushort* vTp = vT + (size_t)bh*64*1024;
    const int nt = (qt >> 3) + 1;     // 128-wide KV tiles

    for (int t = 0; t < nt; ++t) {
        const int tk0 = b*1024 + t*128;
        f32x4 s[8];
        #pragma unroll
        for (int n = 0; n < 8; ++n) s[n] = (f32x4){0.f,0.f,0.f,0.f};
        #pragma unroll
        for (int kk = 0; kk < 2; ++kk)
            #pragma unroll
            for (int n = 0; n < 8; ++n) {
                short8 bk = *(const short8*)&Kp[(size_t)(tk0 + n*16 + lq)*1024 + h*64 + kk*32 + lg*8];
                s[n] = __builtin_amdgcn_mfma_f32_16x16x32_bf16(aq[kk], bk, s[n], 0, 0, 0);
            }

        // scale + causal mask: q = qt*16 + lg*4 + r, k = t*128 + n*16 + lq
        const bool diag = (t == nt-1);
        if (diag) {
            #pragma unroll
            for (int n = 0; n < 8; ++n)
                #pragma unroll
                for (int r = 0; r < 4; ++r) {
                    float v = s[n][r] * 0.125f;
                    if (t*128 + n*16 + lq > qt*16 + lg*4 + r) v = -1e9f;
                    s[n][r] = v;
                }
        } else {
            #pragma unroll
            for (int n = 0; n < 8; ++n)
                #pragma unroll
                for (int r = 0; r < 4; ++r) s[n][r] *= 0.125f;
        }

        #pragma unroll
        for (int r = 0; r < 4; ++r) {
            float rm = fmaxf(fmaxf(fmaxf(s[0][r], s[1][r]), fmaxf(s[2][r], s[3][r])),
                             fmaxf(fmaxf(s[4][r], s[5][r]), fmaxf(s[6][r], s[7][r])));
            rm = fmaxf(rm, __shfl_xor(rm, 1));
            rm = fmaxf(rm, __shfl_xor(rm, 2));
            rm = fmaxf(rm, __shfl_xor(rm, 4));
            rm = fmaxf(rm, __shfl_xor(rm, 8));
            float mnew = fmaxf(m[r], rm);
            float corr = __expf(m[r] - mnew);
            float ps = 0.f;
            #pragma unroll
            for (int n = 0; n < 8; ++n) {
                float p = __expf(s[n][r] - mnew);
                s[n][r] = p; ps += p;
            }
            ps += __shfl_xor(ps, 1);
            ps += __shfl_xor(ps, 2);
            ps += __shfl_xor(ps, 4);
            ps += __shfl_xor(ps, 8);
            l[r] = l[r]*corr + ps;
            m[r] = mnew;
            o[0][r] *= corr; o[1][r] *= corr; o[2][r] *= corr; o[3][r] *= corr;
        }

        // P (bf16-packed) -> pTu[k][q/2] (uint writes, same-wave FIFO)
        #pragma unroll
        for (int n = 0; n < 8; ++n) {
            unsigned int lo = (unsigned int)f2b(s[n][0]) | ((unsigned int)f2b(s[n][1]) << 16);
            unsigned int hi = (unsigned int)f2b(s[n][2]) | ((unsigned int)f2b(s[n][3]) << 16);
            pTu[n*16 + lq][lg*2]     = lo;
            pTu[n*16 + lq][lg*2 + 1] = hi;
        }
        __builtin_amdgcn_wave_barrier();

        short8 pa[4];
        #pragma unroll
        for (int kk = 0; kk < 4; ++kk)
            #pragma unroll
            for (int j = 0; j < 8; ++j) {
                unsigned int u = pTu[kk*32 + lg*8 + j][lq >> 1];
                pa[kk][j] = (short)(ushort)(u >> ((lq & 1) * 16));
            }
        __builtin_amdgcn_wave_barrier();

        #pragma unroll
        for (int kk = 0; kk < 4; ++kk)
            #pragma unroll
            for (int n = 0; n < 4; ++n) {
                short8 bv = *(const short8*)&vTp[(size_t)(n*16 + lq)*1024 + t*128 + kk*32 + lg*8];
                o[n] = __builtin_amdgcn_mfma_f32_16x16x32_bf16(pa[kk], bv, o[n], 0, 0, 0);
            }
    }

    #pragma unroll
    for (int r = 0; r < 4; ++r) {
        float inv = 1.f / l[r];
        int row = b*1024 + qt*16 + lg*4 + r;
        #pragma unroll
        for (int n = 0; n < 4; ++n)
            ctxb[(size_t)row*1024 + h*64 + n*16 + lq] = f2b(o[n][r] * inv);
    }
}

// ---------------------------------------------------------------------------
// Kernel 6: out = ctx(bf16) @ wT(bf16)^T + bias, MFMA. 128x64 block tile,
// grid (16,32)=512 blocks (2/CU -> 2 waves/SIMD TLP). Wave = 64x32 output.
// ---------------------------------------------------------------------------
__global__ __launch_bounds__(256) void proj_kernel(
    const ushort* __restrict__ A,     // ctx bf16 [4096][1024]
    const ushort* __restrict__ Bt,    // wT bf16 [1024(n)][1024(k)]
    const float* __restrict__ bias,   // [1024]
    float* __restrict__ out)          // [4096][1024]
{
    const int bn = blockIdx.x, bm = blockIdx.y;
    const int tid = threadIdx.x, w = tid >> 6, lane = tid & 63;
    const int wm = w >> 1, wn = w & 1;
    const int lq = lane & 15, lg = lane >> 4;
    const int row0 = bm*128 + wm*64;
    const int col0 = bn*64 + wn*32;

    f32x4 acc[4][2];
    #pragma unroll
    for (int i = 0; i < 4; ++i)
        #pragma unroll
        for (int j = 0; j < 2; ++j) acc[i][j] = (f32x4){0.f,0.f,0.f,0.f};

    for (int k0 = 0; k0 < 1024; k0 += 32) {
        short8 a[4], bfr[2];
        #pragma unroll
        for (int i = 0; i < 4; ++i)
            a[i] = *(const short8*)&A[(size_t)(row0 + i*16 + lq)*1024 + k0 + lg*8];
        #pragma unroll
        for (int j = 0; j < 2; ++j)
            bfr[j] = *(const short8*)&Bt[(size_t)(col0 + j*16 + lq)*1024 + k0 + lg*8];
        #pragma unroll
        for (int i = 0; i < 4; ++i)
            #pragma unroll
            for (int j = 0; j < 2; ++j)
                acc[i][j] = __builtin_amdgcn_mfma_f32_16x16x32_bf16(a[i], bfr[j], acc[i][j], 0, 0, 0);
    }

    #pragma unroll
    for (int i = 0; i < 4; ++i)
        #pragma unroll
        for (int j = 0; j < 2; ++j) {
            int col = col0 + j*16 + lq;
            float bb = bias[col];
            #pragma unroll
            for (int r = 0; r < 4; ++r)
                out[(size_t)(row0 + i*16 + lg*4 + r)*1024 + col] = acc[i][j][r] + bb;
        }
}

// ---------------------------------------------------------------------------
extern "C" void kernel_launch(void* const* d_in, const int* in_sizes, int n_in,
                              void* d_out, int out_size, void* d_ws, size_t ws_size,
                              hipStream_t stream) {
    (void)in_sizes; (void)n_in; (void)out_size; (void)ws_size;
    const float* x      = (const float*)d_in[0];
    const float* dw     = (const float*)d_in[1];
    const float* db     = (const float*)d_in[2];
    const float* ntl    = (const float*)d_in[3];
    const float* gate_w = (const float*)d_in[4];
    const float* gate_b = (const float*)d_in[5];
    const float* leaf   = (const float*)d_in[6];
    const float* out_w  = (const float*)d_in[7];
    const float* out_b  = (const float*)d_in[8];
    float* out = (float*)d_out;

    // ws layout (bytes): coeffb@0 (0.75MB) | Wb@1MB (0.2MB) | qkvb@2MB (16MB)
    //                    vT@20MB (8MB) | ctxb@30MB (8MB) | wT@40MB (2MB) | leafT@44MB (0.6MB)
    ushort* coeffb = (ushort*)d_ws;
    ushort* Wb     = (ushort*)((char*)d_ws + ((size_t)1u  << 20));
    ushort* qkvb   = (ushort*)((char*)d_ws + ((size_t)2u  << 20));
    ushort* vT     = (ushort*)((char*)d_ws + ((size_t)20u << 20));
    ushort* ctxb   = (ushort*)((char*)d_ws + ((size_t)30u << 20));
    ushort* wT     = (ushort*)((char*)d_ws + ((size_t)40u << 20));
    ushort* leafT  = (ushort*)((char*)d_ws + ((size_t)44u << 20));

    hipLaunchKernelGGL(wb_kernel,      dim3(48),      dim3(256), 0, stream,
                       dw, gate_w, Wb);
    hipLaunchKernelGGL(lt_kernel,      dim3(16, 3),   dim3(256), 0, stream,
                       leaf, leafT);
    hipLaunchKernelGGL(wtrans_kernel,  dim3(16, 16),  dim3(256), 0, stream,
                       out_w, wT);
    hipLaunchKernelGGL(route3_kernel,  dim3(256),     dim3(512), 0, stream,
                       x, Wb, db, ntl, gate_b, coeffb);
    hipLaunchKernelGGL(mix_kernel,     dim3(64, 24),  dim3(256), 0, stream,
                       coeffb, leafT, qkvb, vT);
    hipLaunchKernelGGL(attn_kernel,    dim3(4096),    dim3(64),  0, stream,
                       qkvb, vT, ctxb);
    hipLaunchKernelGGL(proj_kernel,    dim3(16, 32),  dim3(256), 0, stream,
                       ctxb, wT, out_b, out);
}